// Round 5
// baseline (560.598 us; speedup 1.0000x reference)
//
#include <hip/hip_runtime.h>
#include <hip/hip_fp16.h>

typedef _Float16 half4v __attribute__((ext_vector_type(4)));
typedef _Float16 half8v __attribute__((ext_vector_type(8)));
typedef float floatx4 __attribute__((ext_vector_type(4)));

#define GLOBAL_AS __attribute__((address_space(1)))
#define LDS_AS __attribute__((address_space(3)))

__device__ __forceinline__ void async_copy16(const _Float16* g, _Float16* l) {
    __builtin_amdgcn_global_load_lds((const GLOBAL_AS unsigned int*)g,
                                     (LDS_AS unsigned int*)l, 16, 0, 0);
}

// Stage R x 64-half tile (global row stride ldg halves) into LDS (row stride 64,
// XOR chunk swizzle: slot (row,c) holds global chunk c^(row&7)).
template <int R>
__device__ __forceinline__ void stage_tile(const _Float16* g, long ldg,
                                           _Float16* lds, int wave, int lane) {
    const int rl = lane >> 3;
    const int gc = (lane & 7) ^ rl;
#pragma unroll
    for (int i = 0; i < (R >> 5); ++i) {
        const int br = wave * (R >> 2) + i * 8;
        async_copy16(g + (long)(br + rl) * ldg + gc * 8, lds + br * 64);
    }
}

// ---------------- k_prep: all converts + transposes + bitmask pack ----------------
__device__ __forceinline__ void tr_tile(const float* __restrict__ in,
                                        _Float16* __restrict__ out, int R, int C,
                                        int br, int bc, int tid, float (*tile)[33]) {
    int tx = tid & 31, ty = tid >> 5;
#pragma unroll
    for (int i = 0; i < 32; i += 8)
        tile[ty + i][tx] = in[(size_t)(br + ty + i) * C + bc + tx];
    __syncthreads();
#pragma unroll
    for (int i = 0; i < 32; i += 8)
        out[(size_t)(bc + ty + i) * R + br + tx] = (_Float16)tile[tx][ty + i];
    __syncthreads();
}

__global__ __launch_bounds__(256) void k_prep(
    const float* __restrict__ search_x, const float* __restrict__ search_y,
    const float* __restrict__ query_x, const int* __restrict__ mask,
    const float* __restrict__ Wk, const float* __restrict__ Wq,
    _Float16* __restrict__ xh, _Float16* __restrict__ qh,
    _Float16* __restrict__ wkT, _Float16* __restrict__ wqT,
    _Float16* __restrict__ yT, unsigned int* __restrict__ bm) {
    __shared__ float tile[32][33];
    const int bx = blockIdx.x, tid = threadIdx.x;
    if (bx < 2048) {
        // pack mask 32M int32 -> 1M-word bitmask (bit j of word w = col w*32+j)
        const int gw = bx * 4 + (tid >> 6);
        const int lane = tid & 63;
        for (int it = 0; it < 64; ++it) {
            const int idx = (gw * 64 + it) * 64 + lane;
            const int v = mask[idx];
            unsigned long long b = __ballot(v > 0);
            if (lane == 0) bm[idx >> 5] = (unsigned int)b;
            if (lane == 32) bm[idx >> 5] = (unsigned int)(b >> 32);
        }
    } else if (bx < 2560) {
        const int base0 = (bx - 2048) * 256 + tid;
        for (int it = 0; it < 16; ++it) {
            const int i = (it * 512 * 256 + base0) * 4;
            float4 v = *(const float4*)(search_x + i);
            half4v h; h[0]=(_Float16)v.x; h[1]=(_Float16)v.y; h[2]=(_Float16)v.z; h[3]=(_Float16)v.w;
            *(half4v*)(xh + i) = h;
        }
    } else if (bx < 2816) {
        const int base0 = (bx - 2560) * 256 + tid;
        for (int it = 0; it < 16; ++it) {
            const int i = (it * 256 * 256 + base0) * 4;
            float4 v = *(const float4*)(query_x + i);
            half4v h; h[0]=(_Float16)v.x; h[1]=(_Float16)v.y; h[2]=(_Float16)v.z; h[3]=(_Float16)v.w;
            *(half4v*)(qh + i) = h;
        }
    } else if (bx < 2944) {
        for (int it = 0; it < 16; ++it) {
            const int t = (bx - 2816) * 16 + it;          // 2048 tiles
            tr_tile(search_y, yT, 8192, 256, (t >> 3) * 32, (t & 7) * 32, tid, tile);
        }
    } else if (bx < 2976) {
        for (int it = 0; it < 16; ++it) {
            const int t = (bx - 2944) * 16 + it;          // 512 tiles
            tr_tile(Wk, wkT, 1024, 512, (t >> 4) * 32, (t & 15) * 32, tid, tile);
        }
    } else {
        for (int it = 0; it < 16; ++it) {
            const int t = (bx - 2976) * 16 + it;
            tr_tile(Wq, wqT, 1024, 512, (t >> 4) * 32, (t & 15) * 32, tid, tile);
        }
    }
}

// ---------------- k_proj: keys = x@Wk and qk = q@Wq in one dispatch ----------------
// 128x128 tile, BK=64, ping-pong LDS (1 barrier/kt, staging overlaps MFMA).
__global__ __launch_bounds__(256, 2) void k_proj(const _Float16* __restrict__ xh,
                                                 const _Float16* __restrict__ qh,
                                                 const _Float16* __restrict__ wkT,
                                                 const _Float16* __restrict__ wqT,
                                                 _Float16* __restrict__ keys,
                                                 _Float16* __restrict__ qk) {
    __shared__ __align__(16) _Float16 As[2][128 * 64];
    __shared__ __align__(16) _Float16 Bs[2][128 * 64];
    const int tid = threadIdx.x, lane = tid & 63, wave = tid >> 6;
    const int wm = (wave >> 1) * 64, wn = (wave & 1) * 64;
    const int quad = lane >> 4, lr = lane & 15;
    const bool isK = blockIdx.y < 64;
    const _Float16* A = isK ? xh : qh;
    const _Float16* B = isK ? wkT : wqT;
    _Float16* C = isK ? keys : qk;
    const long m0 = (long)(isK ? blockIdx.y : blockIdx.y - 64) * 128;
    const long n0 = (long)blockIdx.x * 128;

    floatx4 acc[4][4] = {};
    stage_tile<128>(A + m0 * 1024, 1024, As[0], wave, lane);
    stage_tile<128>(B + n0 * 1024, 1024, Bs[0], wave, lane);
    for (int ktI = 0; ktI < 16; ++ktI) {
        __syncthreads();                      // drains stage of buf cb
        const int cb = ktI & 1;
        if (ktI < 15) {
            stage_tile<128>(A + m0 * 1024 + (ktI + 1) * 64, 1024, As[cb ^ 1], wave, lane);
            stage_tile<128>(B + n0 * 1024 + (ktI + 1) * 64, 1024, Bs[cb ^ 1], wave, lane);
        }
#pragma unroll
        for (int kk = 0; kk < 64; kk += 32) {
            const int sl = ((((kk >> 3) + quad) ^ (lr & 7)) * 8);
            half8v af[4], bf[4];
#pragma unroll
            for (int i = 0; i < 4; ++i) af[i] = *(const half8v*)&As[cb][(wm + i * 16 + lr) * 64 + sl];
#pragma unroll
            for (int j = 0; j < 4; ++j) bf[j] = *(const half8v*)&Bs[cb][(wn + j * 16 + lr) * 64 + sl];
#pragma unroll
            for (int i = 0; i < 4; ++i)
#pragma unroll
                for (int j = 0; j < 4; ++j)
                    acc[i][j] = __builtin_amdgcn_mfma_f32_16x16x32_f16(af[i], bf[j], acc[i][j], 0, 0, 0);
        }
    }
#pragma unroll
    for (int i = 0; i < 4; ++i) {
        long rbase = m0 + wm + i * 16 + quad * 4;
#pragma unroll
        for (int j = 0; j < 4; ++j) {
            long col = n0 + wn + j * 16 + lr;
#pragma unroll
            for (int r = 0; r < 4; ++r)
                C[(rbase + r) * 512 + col] = (_Float16)acc[i][j][r];
        }
    }
}

// ---------------- k_flash v2 ----------------
// grid (16 chunks x 64 q-tiles). Block: 64 q-rows x 512 keys (4 t-tiles of 128).
// Wave w owns q-rows [16w,16w+16): softmax stats are wave-local (shfl over lr).
// Phase A ping-pong staging; mask via L2-resident bitmask; Ys h0 staged under B's VALU.
#define SCALE 0.04419417382415922f
__global__ __launch_bounds__(256, 3) void k_flash(
    const _Float16* __restrict__ qk, const _Float16* __restrict__ keys,
    const _Float16* __restrict__ yT, const unsigned int* __restrict__ bm,
    float* __restrict__ part, float* __restrict__ ml) {
    __shared__ __align__(16) char smem[50176];
    _Float16* Qs[2] = {(_Float16*)smem, (_Float16*)(smem + 8192)};       // [64][64] x2
    _Float16* Ks[2] = {(_Float16*)(smem + 16384), (_Float16*)(smem + 32768)}; // [128][64] x2
    _Float16* Ps = (_Float16*)smem;                                      // [64][136]
    _Float16* Ys = (_Float16*)(smem + 17408);                            // [256][64]

    const int tid = threadIdx.x, lane = tid & 63, wave = tid >> 6;
    const int quad = lane >> 4, lr = lane & 15;
    const int nc = blockIdx.x;
    const int q0 = blockIdx.y * 64;
    const long n0 = (long)nc * 512;

    floatx4 acc_o[16] = {};
    float m_reg[4], l_reg[4];
#pragma unroll
    for (int r = 0; r < 4; ++r) { m_reg[r] = -3.0e38f; l_reg[r] = 0.f; }

    const _Float16* Qg = qk + (long)q0 * 512;

    stage_tile<64>(Qg, 512, Qs[0], wave, lane);
    stage_tile<128>(keys + n0 * 512, 512, Ks[0], wave, lane);

#pragma unroll 1
    for (int t = 0; t < 4; ++t) {
        const _Float16* Kg = keys + (n0 + t * 128) * 512;
        floatx4 acc_s[8] = {};
        // ---- phase A: S[16 rows/wave][128] over K=512, ping-pong ----
        for (int ktI = 0; ktI < 8; ++ktI) {
            __syncthreads();
            const int cb = ktI & 1;
            if (ktI < 7) {
                stage_tile<64>(Qg + (ktI + 1) * 64, 512, Qs[cb ^ 1], wave, lane);
                stage_tile<128>(Kg + (ktI + 1) * 64, 512, Ks[cb ^ 1], wave, lane);
            }
#pragma unroll
            for (int kk = 0; kk < 64; kk += 32) {
                const int sl = ((((kk >> 3) + quad) ^ (lr & 7)) * 8);
                half8v af = *(const half8v*)&Qs[cb][(wave * 16 + lr) * 64 + sl];
#pragma unroll
                for (int j = 0; j < 8; ++j) {
                    half8v bf = *(const half8v*)&Ks[cb][(j * 16 + lr) * 64 + sl];
                    acc_s[j] = __builtin_amdgcn_mfma_f32_16x16x32_f16(af, bf, acc_s[j], 0, 0, 0);
                }
            }
        }
        __syncthreads();   // A-end: all LDS reads done; A-buffers reusable
        // ---- phase B (no barriers until end) ----
        stage_tile<256>(yT + n0 + t * 128, 8192, Ys, wave, lane);  // h0, hides under VALU
        unsigned long long mlo[4], mhi[4];
#pragma unroll
        for (int r = 0; r < 4; ++r) {
            const unsigned int* bmr = bm + (size_t)(q0 + wave * 16 + quad * 4 + r) * 256 + nc * 16 + t * 4;
            mlo[r] = *(const unsigned long long*)bmr;
            mhi[r] = *(const unsigned long long*)(bmr + 2);
        }
        float rmax[4] = {-3.0e38f, -3.0e38f, -3.0e38f, -3.0e38f};
#pragma unroll
        for (int j = 0; j < 8; ++j) {
            const int bit = (j & 3) * 16 + lr;
#pragma unroll
            for (int r = 0; r < 4; ++r) {
                const unsigned long long w = (j < 4) ? mlo[r] : mhi[r];
                float v = ((w >> bit) & 1ull) ? acc_s[j][r] * SCALE : -3.0e38f;
                acc_s[j][r] = v;
                rmax[r] = fmaxf(rmax[r], v);
            }
        }
        float mnew[4], alpha[4], rsum[4];
#pragma unroll
        for (int r = 0; r < 4; ++r) {
#pragma unroll
            for (int m = 1; m < 16; m <<= 1)
                rmax[r] = fmaxf(rmax[r], __shfl_xor(rmax[r], m, 64));
            mnew[r] = fmaxf(m_reg[r], rmax[r]);
            alpha[r] = __expf(m_reg[r] - mnew[r]);
            m_reg[r] = mnew[r];
            rsum[r] = 0.f;
        }
#pragma unroll
        for (int j = 0; j < 8; ++j)
#pragma unroll
            for (int r = 0; r < 4; ++r) {
                float p = (acc_s[j][r] > -1.0e37f) ? __expf(acc_s[j][r] - mnew[r]) : 0.f;
                rsum[r] += p;
                Ps[(wave * 16 + quad * 4 + r) * 136 + j * 16 + lr] = (_Float16)p;
            }
#pragma unroll
        for (int r = 0; r < 4; ++r) {
#pragma unroll
            for (int m = 1; m < 16; m <<= 1)
                rsum[r] += __shfl_xor(rsum[r], m, 64);
            l_reg[r] = l_reg[r] * alpha[r] + rsum[r];
        }
#pragma unroll
        for (int j2 = 0; j2 < 16; ++j2)
#pragma unroll
            for (int r = 0; r < 4; ++r) acc_o[j2][r] *= alpha[r];
        __syncthreads();   // B-end: drains Ys h0; Ps visible
        // ---- phase C: O[16 rows/wave][256] += P @ Y ----
#pragma unroll
        for (int h = 0; h < 2; ++h) {
            if (h == 1) {
                __syncthreads();                                   // Ys h0 reads done
                stage_tile<256>(yT + n0 + t * 128 + 64, 8192, Ys, wave, lane);
                __syncthreads();                                   // drain h1
            }
#pragma unroll
            for (int kkk = 0; kkk < 64; kkk += 32) {
                half8v pa = *(const half8v*)&Ps[(wave * 16 + lr) * 136 + h * 64 + kkk + quad * 8];
                const int sl = ((((kkk >> 3) + quad) ^ (lr & 7)) * 8);
#pragma unroll
                for (int j2 = 0; j2 < 16; ++j2) {
                    half8v yb = *(const half8v*)&Ys[(j2 * 16 + lr) * 64 + sl];
                    acc_o[j2] = __builtin_amdgcn_mfma_f32_16x16x32_f16(pa, yb, acc_o[j2], 0, 0, 0);
                }
            }
        }
        __syncthreads();   // C-end: Ys/Ps reads done; safe to overwrite with next A-stage
        if (t < 3) {
            stage_tile<64>(Qg, 512, Qs[0], wave, lane);
            stage_tile<128>(keys + (n0 + (t + 1) * 128) * 512, 512, Ks[0], wave, lane);
        }
    }
    // ---- epilogue ----
    float* op = part + ((size_t)nc * 4096 + q0 + wave * 16) * 256;
#pragma unroll
    for (int j2 = 0; j2 < 16; ++j2) {
        const int col = j2 * 16 + lr;
#pragma unroll
        for (int r = 0; r < 4; ++r)
            op[(long)(quad * 4 + r) * 256 + col] = acc_o[j2][r];
    }
    if (lr == 0) {
#pragma unroll
        for (int r = 0; r < 4; ++r) {
            const long row = q0 + wave * 16 + quad * 4 + r;
            ml[(size_t)nc * 4096 + row] = m_reg[r];
            ml[65536 + (size_t)nc * 4096 + row] = l_reg[r];
        }
    }
}

// ---------------- combine 16 chunk partials with softmax merge ----------------
__global__ __launch_bounds__(256) void k_combine(const float* __restrict__ part,
                                                 const float* __restrict__ ml,
                                                 float* __restrict__ out) {
    const int q = blockIdx.x * 4 + (threadIdx.x >> 6);
    const int c = (threadIdx.x & 63) * 4;
    float mz[16], lz[16], M = -3.0e38f;
#pragma unroll
    for (int z = 0; z < 16; ++z) {
        mz[z] = ml[(size_t)z * 4096 + q];
        lz[z] = ml[65536 + (size_t)z * 4096 + q];
        M = fmaxf(M, mz[z]);
    }
    float L = 0.f;
    float4 o = make_float4(0.f, 0.f, 0.f, 0.f);
#pragma unroll
    for (int z = 0; z < 16; ++z) {
        float w = __expf(mz[z] - M);
        L += w * lz[z];
        float4 v = *(const float4*)(part + ((size_t)z * 4096 + q) * 256 + c);
        o.x += w * v.x; o.y += w * v.y; o.z += w * v.z; o.w += w * v.w;
    }
    float inv = (L > 0.f) ? 1.f / L : 0.f;
    o.x *= inv; o.y *= inv; o.z *= inv; o.w *= inv;
    *(float4*)(out + (size_t)q * 256 + c) = o;
}

extern "C" void kernel_launch(void* const* d_in, const int* in_sizes, int n_in,
                              void* d_out, int out_size, void* d_ws, size_t ws_size,
                              hipStream_t stream) {
    const float* search_x = (const float*)d_in[0];  // [8192,1024]
    const float* search_y = (const float*)d_in[1];  // [8192,256]
    const float* query_x  = (const float*)d_in[2];  // [4096,1024]
    const int*   mask     = (const int*)d_in[3];    // [4096,8192]
    const float* Wk       = (const float*)d_in[4];  // [1024,512]
    const float* Wq       = (const float*)d_in[5];  // [1024,512]
    (void)in_sizes; (void)n_in; (void)ws_size; (void)out_size;

    char* p = (char*)d_ws;
    _Float16* xh   = (_Float16*)p; p += (size_t)8192 * 1024 * 2;
    _Float16* qh   = (_Float16*)p; p += (size_t)4096 * 1024 * 2;
    _Float16* wkT  = (_Float16*)p; p += (size_t)512 * 1024 * 2;
    _Float16* wqT  = (_Float16*)p; p += (size_t)512 * 1024 * 2;
    _Float16* yT   = (_Float16*)p; p += (size_t)256 * 8192 * 2;
    _Float16* keys = (_Float16*)p; p += (size_t)8192 * 512 * 2;
    _Float16* qk   = (_Float16*)p; p += (size_t)4096 * 512 * 2;
    unsigned int* bmw = (unsigned int*)p; p += (size_t)4096 * 256 * 4;
    float*    part = (float*)p;    p += (size_t)16 * 4096 * 256 * 4;
    float*    ml   = (float*)p;    p += (size_t)2 * 16 * 4096 * 4;

    k_prep<<<3008, 256, 0, stream>>>(search_x, search_y, query_x, mask, Wk, Wq,
                                     xh, qh, wkT, wqT, yT, bmw);
    k_proj<<<dim3(4, 96), 256, 0, stream>>>(xh, qh, wkT, wqT, keys, qk);
    k_flash<<<dim3(16, 64), 256, 0, stream>>>(qk, keys, yT, bmw, part, ml);
    k_combine<<<1024, 256, 0, stream>>>(part, ml, (float*)d_out);
}

// Round 6
// 414.518 us; speedup vs baseline: 1.3524x; 1.3524x over previous
//
#include <hip/hip_runtime.h>
#include <hip/hip_fp16.h>

typedef _Float16 half4v __attribute__((ext_vector_type(4)));
typedef _Float16 half8v __attribute__((ext_vector_type(8)));
typedef float floatx4 __attribute__((ext_vector_type(4)));

#define GLOBAL_AS __attribute__((address_space(1)))
#define LDS_AS __attribute__((address_space(3)))

__device__ __forceinline__ void async_copy16(const _Float16* g, _Float16* l) {
    __builtin_amdgcn_global_load_lds((const GLOBAL_AS unsigned int*)g,
                                     (LDS_AS unsigned int*)l, 16, 0, 0);
}

// Stage R x 64-half tile (global row stride ldg halves) into LDS (row stride 64,
// XOR chunk swizzle: slot (row,c) holds global chunk c^(row&7)).
template <int R>
__device__ __forceinline__ void stage_tile(const _Float16* g, long ldg,
                                           _Float16* lds, int wave, int lane) {
    const int rl = lane >> 3;
    const int gc = (lane & 7) ^ rl;
#pragma unroll
    for (int i = 0; i < (R >> 5); ++i) {
        const int br = wave * (R >> 2) + i * 8;
        async_copy16(g + (long)(br + rl) * ldg + gc * 8, lds + br * 64);
    }
}

// ---------------- k_prep: all converts + transposes + bitmask pack ----------------
__device__ __forceinline__ void tr_tile(const float* __restrict__ in,
                                        _Float16* __restrict__ out, int R, int C,
                                        int br, int bc, int tid, float (*tile)[33]) {
    int tx = tid & 31, ty = tid >> 5;
#pragma unroll
    for (int i = 0; i < 32; i += 8)
        tile[ty + i][tx] = in[(size_t)(br + ty + i) * C + bc + tx];
    __syncthreads();
#pragma unroll
    for (int i = 0; i < 32; i += 8)
        out[(size_t)(bc + ty + i) * R + br + tx] = (_Float16)tile[tx][ty + i];
    __syncthreads();
}

__global__ __launch_bounds__(256) void k_prep(
    const float* __restrict__ search_x, const float* __restrict__ search_y,
    const float* __restrict__ query_x, const int* __restrict__ mask,
    const float* __restrict__ Wk, const float* __restrict__ Wq,
    _Float16* __restrict__ xh, _Float16* __restrict__ qh,
    _Float16* __restrict__ wkT, _Float16* __restrict__ wqT,
    _Float16* __restrict__ yT, unsigned int* __restrict__ bm) {
    __shared__ float tile[32][33];
    const int bx = blockIdx.x, tid = threadIdx.x;
    if (bx < 2048) {
        // pack mask 32M int32 -> 1M-word bitmask (bit j of word w = col w*32+j)
        const int gw = bx * 4 + (tid >> 6);
        const int lane = tid & 63;
        for (int it = 0; it < 64; ++it) {
            const int idx = (gw * 64 + it) * 64 + lane;
            const int v = mask[idx];
            unsigned long long b = __ballot(v > 0);
            if (lane == 0) bm[idx >> 5] = (unsigned int)b;
            if (lane == 32) bm[idx >> 5] = (unsigned int)(b >> 32);
        }
    } else if (bx < 2560) {
        const int base0 = (bx - 2048) * 256 + tid;
        for (int it = 0; it < 16; ++it) {
            const int i = (it * 512 * 256 + base0) * 4;
            float4 v = *(const float4*)(search_x + i);
            half4v h; h[0]=(_Float16)v.x; h[1]=(_Float16)v.y; h[2]=(_Float16)v.z; h[3]=(_Float16)v.w;
            *(half4v*)(xh + i) = h;
        }
    } else if (bx < 2816) {
        const int base0 = (bx - 2560) * 256 + tid;
        for (int it = 0; it < 16; ++it) {
            const int i = (it * 256 * 256 + base0) * 4;
            float4 v = *(const float4*)(query_x + i);
            half4v h; h[0]=(_Float16)v.x; h[1]=(_Float16)v.y; h[2]=(_Float16)v.z; h[3]=(_Float16)v.w;
            *(half4v*)(qh + i) = h;
        }
    } else if (bx < 2944) {
        for (int it = 0; it < 16; ++it) {
            const int t = (bx - 2816) * 16 + it;          // 2048 tiles
            tr_tile(search_y, yT, 8192, 256, (t >> 3) * 32, (t & 7) * 32, tid, tile);
        }
    } else if (bx < 2976) {
        for (int it = 0; it < 16; ++it) {
            const int t = (bx - 2944) * 16 + it;          // 512 tiles
            tr_tile(Wk, wkT, 1024, 512, (t >> 4) * 32, (t & 15) * 32, tid, tile);
        }
    } else {
        for (int it = 0; it < 16; ++it) {
            const int t = (bx - 2976) * 16 + it;
            tr_tile(Wq, wqT, 1024, 512, (t >> 4) * 32, (t & 15) * 32, tid, tile);
        }
    }
}

// ---------------- k_proj: keys = x@Wk and qk = q@Wq in one dispatch ----------------
// 128x128 tile, BK=64, ping-pong LDS (1 barrier/kt, staging overlaps MFMA).
__global__ __launch_bounds__(256, 2) void k_proj(const _Float16* __restrict__ xh,
                                                 const _Float16* __restrict__ qh,
                                                 const _Float16* __restrict__ wkT,
                                                 const _Float16* __restrict__ wqT,
                                                 _Float16* __restrict__ keys,
                                                 _Float16* __restrict__ qk) {
    __shared__ __align__(16) _Float16 As[2][128 * 64];
    __shared__ __align__(16) _Float16 Bs[2][128 * 64];
    const int tid = threadIdx.x, lane = tid & 63, wave = tid >> 6;
    const int wm = (wave >> 1) * 64, wn = (wave & 1) * 64;
    const int quad = lane >> 4, lr = lane & 15;
    const bool isK = blockIdx.y < 64;
    const _Float16* A = isK ? xh : qh;
    const _Float16* B = isK ? wkT : wqT;
    _Float16* C = isK ? keys : qk;
    const long m0 = (long)(isK ? blockIdx.y : blockIdx.y - 64) * 128;
    const long n0 = (long)blockIdx.x * 128;

    floatx4 acc[4][4] = {};
    stage_tile<128>(A + m0 * 1024, 1024, As[0], wave, lane);
    stage_tile<128>(B + n0 * 1024, 1024, Bs[0], wave, lane);
    for (int ktI = 0; ktI < 16; ++ktI) {
        __syncthreads();                      // drains stage of buf cb
        const int cb = ktI & 1;
        if (ktI < 15) {
            stage_tile<128>(A + m0 * 1024 + (ktI + 1) * 64, 1024, As[cb ^ 1], wave, lane);
            stage_tile<128>(B + n0 * 1024 + (ktI + 1) * 64, 1024, Bs[cb ^ 1], wave, lane);
        }
#pragma unroll
        for (int kk = 0; kk < 64; kk += 32) {
            const int sl = ((((kk >> 3) + quad) ^ (lr & 7)) * 8);
            half8v af[4], bf[4];
#pragma unroll
            for (int i = 0; i < 4; ++i) af[i] = *(const half8v*)&As[cb][(wm + i * 16 + lr) * 64 + sl];
#pragma unroll
            for (int j = 0; j < 4; ++j) bf[j] = *(const half8v*)&Bs[cb][(wn + j * 16 + lr) * 64 + sl];
#pragma unroll
            for (int i = 0; i < 4; ++i)
#pragma unroll
                for (int j = 0; j < 4; ++j)
                    acc[i][j] = __builtin_amdgcn_mfma_f32_16x16x32_f16(af[i], bf[j], acc[i][j], 0, 0, 0);
        }
    }
#pragma unroll
    for (int i = 0; i < 4; ++i) {
        long rbase = m0 + wm + i * 16 + quad * 4;
#pragma unroll
        for (int j = 0; j < 4; ++j) {
            long col = n0 + wn + j * 16 + lr;
#pragma unroll
            for (int r = 0; r < 4; ++r)
                C[(rbase + r) * 512 + col] = (_Float16)acc[i][j][r];
        }
    }
}

// ---------------- NT GEMM: C[M,N] = scale * A[M,K] @ B[N,K]^T ----------------
// R3-verified m97-style single-buffer structure; no min-waves bound (no spill).
// OUT_MODE 0: f16 store. OUT_MODE 1: fp32 partial store at C + blockIdx.z*M*N.
template <int OUT_MODE>
__global__ __launch_bounds__(256) void k_gemm_nt(const _Float16* __restrict__ A,
                                                 const _Float16* __restrict__ B,
                                                 void* __restrict__ C,
                                                 int M, int N, int K, int kChunk,
                                                 float scale) {
    __shared__ __align__(16) _Float16 As[128 * 64];
    __shared__ __align__(16) _Float16 Bs[128 * 64];
    const int tid = threadIdx.x, lane = tid & 63, wave = tid >> 6;
    const int wm = (wave >> 1) * 64, wn = (wave & 1) * 64;
    const int quad = lane >> 4, lr = lane & 15;
    const long m0 = (long)blockIdx.y * 128, n0 = (long)blockIdx.x * 128;
    const int kBegin = blockIdx.z * kChunk;
    const int kEnd   = kBegin + kChunk;

    floatx4 acc[4][4] = {};
    for (int kt = kBegin; kt < kEnd; kt += 64) {
        stage_tile<128>(A + m0 * K + kt, K, As, wave, lane);
        stage_tile<128>(B + n0 * K + kt, K, Bs, wave, lane);
        __syncthreads();
#pragma unroll
        for (int kk = 0; kk < 64; kk += 32) {
            const int sl = ((((kk >> 3) + quad) ^ (lr & 7)) * 8);
            half8v af[4], bf[4];
#pragma unroll
            for (int i = 0; i < 4; ++i) af[i] = *(const half8v*)&As[(wm + i * 16 + lr) * 64 + sl];
#pragma unroll
            for (int j = 0; j < 4; ++j) bf[j] = *(const half8v*)&Bs[(wn + j * 16 + lr) * 64 + sl];
#pragma unroll
            for (int i = 0; i < 4; ++i)
#pragma unroll
                for (int j = 0; j < 4; ++j)
                    acc[i][j] = __builtin_amdgcn_mfma_f32_16x16x32_f16(af[i], bf[j], acc[i][j], 0, 0, 0);
        }
        __syncthreads();
    }
#pragma unroll
    for (int i = 0; i < 4; ++i) {
        long rbase = m0 + wm + i * 16 + quad * 4;
#pragma unroll
        for (int j = 0; j < 4; ++j) {
            long col = n0 + wn + j * 16 + lr;
#pragma unroll
            for (int r = 0; r < 4; ++r) {
                float val = acc[i][j][r] * scale;
                if (OUT_MODE == 0)
                    ((_Float16*)C)[(rbase + r) * (long)N + col] = (_Float16)val;
                else
                    ((float*)C)[(size_t)blockIdx.z * M * N + (rbase + r) * (long)N + col] = val;
            }
        }
    }
}

// ------- masked softmax (bitmask), in-place on f16 logits [4096][8192] -------
__global__ __launch_bounds__(256) void k_softmax(_Float16* __restrict__ logits,
                                                 const unsigned int* __restrict__ bm) {
    const int q   = blockIdx.x;
    const int tid = threadIdx.x;
    _Float16* row = logits + (size_t)q * 8192;
    const unsigned int* bmr = bm + (size_t)q * 256;

    float v[32];
    unsigned mb = 0;
    float lmax = -3.0e38f;
#pragma unroll
    for (int i = 0; i < 8; ++i) {
        int base = i * 1024 + tid * 4;
        half4v h = *(const half4v*)(row + base);
        unsigned bits = (bmr[base >> 5] >> ((tid & 7) * 4)) & 0xFu;
#pragma unroll
        for (int j = 0; j < 4; ++j) {
            v[i * 4 + j] = (float)h[j];
            if ((bits >> j) & 1u) {
                mb |= 1u << (i * 4 + j);
                lmax = fmaxf(lmax, v[i * 4 + j]);
            }
        }
    }
#pragma unroll
    for (int off = 32; off > 0; off >>= 1) lmax = fmaxf(lmax, __shfl_xor(lmax, off, 64));
    __shared__ float redmax[4], redsum[4];
    if ((tid & 63) == 0) redmax[tid >> 6] = lmax;
    __syncthreads();
    lmax = fmaxf(fmaxf(redmax[0], redmax[1]), fmaxf(redmax[2], redmax[3]));

    float lsum = 0.f;
#pragma unroll
    for (int i = 0; i < 32; ++i) {
        float e = ((mb >> i) & 1u) ? __expf(v[i] - lmax) : 0.f;
        v[i] = e;
        lsum += e;
    }
#pragma unroll
    for (int off = 32; off > 0; off >>= 1) lsum += __shfl_xor(lsum, off, 64);
    if ((tid & 63) == 0) redsum[tid >> 6] = lsum;
    __syncthreads();
    lsum = redsum[0] + redsum[1] + redsum[2] + redsum[3];
    float inv = lsum > 0.f ? 1.f / lsum : 0.f;

#pragma unroll
    for (int i = 0; i < 8; ++i) {
        int base = i * 1024 + tid * 4;
        half4v h;
#pragma unroll
        for (int j = 0; j < 4; ++j) h[j] = (_Float16)(v[i * 4 + j] * inv);
        *(half4v*)(row + base) = h;
    }
}

// ---------------- sum 8 fp32 partials [8][n] -> out[n] ----------------
__global__ __launch_bounds__(256) void k_reduce8(const float* __restrict__ part,
                                                 float* __restrict__ out, int n) {
    int i = (blockIdx.x * 256 + threadIdx.x) * 4;
    if (i >= n) return;
    float4 s = *(const float4*)(part + i);
#pragma unroll
    for (int z = 1; z < 8; ++z) {
        float4 v = *(const float4*)(part + (size_t)z * n + i);
        s.x += v.x; s.y += v.y; s.z += v.z; s.w += v.w;
    }
    *(float4*)(out + i) = s;
}

extern "C" void kernel_launch(void* const* d_in, const int* in_sizes, int n_in,
                              void* d_out, int out_size, void* d_ws, size_t ws_size,
                              hipStream_t stream) {
    const float* search_x = (const float*)d_in[0];  // [8192,1024]
    const float* search_y = (const float*)d_in[1];  // [8192,256]
    const float* query_x  = (const float*)d_in[2];  // [4096,1024]
    const int*   mask     = (const int*)d_in[3];    // [4096,8192]
    const float* Wk       = (const float*)d_in[4];  // [1024,512]
    const float* Wq       = (const float*)d_in[5];  // [1024,512]
    (void)in_sizes; (void)n_in; (void)ws_size; (void)out_size;

    char* p = (char*)d_ws;
    _Float16* xh   = (_Float16*)p; p += (size_t)8192 * 1024 * 2;
    _Float16* qh   = (_Float16*)p; p += (size_t)4096 * 1024 * 2;
    _Float16* wkT  = (_Float16*)p; p += (size_t)512 * 1024 * 2;
    _Float16* wqT  = (_Float16*)p; p += (size_t)512 * 1024 * 2;
    _Float16* yT   = (_Float16*)p; p += (size_t)256 * 8192 * 2;
    _Float16* keys = (_Float16*)p; p += (size_t)8192 * 512 * 2;
    _Float16* qk   = (_Float16*)p; p += (size_t)4096 * 512 * 2;
    unsigned int* bmw = (unsigned int*)p; p += (size_t)4096 * 256 * 4;
    _Float16* lg   = (_Float16*)p; p += (size_t)4096 * 8192 * 2;
    float*    part = (float*)p;    p += (size_t)8 * 4096 * 256 * 4;

    // 1) converts + transposes + bitmask pack
    k_prep<<<3008, 256, 0, stream>>>(search_x, search_y, query_x, mask, Wk, Wq,
                                     xh, qh, wkT, wqT, yT, bmw);
    // 2) keys = x@Wk, qk = q@Wq (one dispatch)
    k_proj<<<dim3(4, 96), 256, 0, stream>>>(xh, qh, wkT, wqT, keys, qk);
    // 3) logits = (qk @ keys^T) / sqrt(512)
    k_gemm_nt<0><<<dim3(64, 32, 1), 256, 0, stream>>>(qk, keys, lg, 4096, 8192, 512, 512,
                                                      0.04419417382415922f);
    // 4) masked softmax in-place (bitmask)
    k_softmax<<<4096, 256, 0, stream>>>(lg, bmw);
    // 5) out = p @ y, split-K=8 -> fp32 partials, then reduce
    k_gemm_nt<1><<<dim3(2, 32, 8), 256, 0, stream>>>(lg, yT, part, 4096, 256, 8192, 1024, 1.0f);
    k_reduce8<<<1024, 256, 0, stream>>>(part, (float*)d_out, 4096 * 256);
}

// Round 7
// 378.120 us; speedup vs baseline: 1.4826x; 1.0963x over previous
//
#include <hip/hip_runtime.h>
#include <hip/hip_fp16.h>

typedef _Float16 half4v __attribute__((ext_vector_type(4)));
typedef _Float16 half8v __attribute__((ext_vector_type(8)));
typedef float floatx4 __attribute__((ext_vector_type(4)));

#define GLOBAL_AS __attribute__((address_space(1)))
#define LDS_AS __attribute__((address_space(3)))

__device__ __forceinline__ void async_copy16(const _Float16* g, _Float16* l) {
    __builtin_amdgcn_global_load_lds((const GLOBAL_AS unsigned int*)g,
                                     (LDS_AS unsigned int*)l, 16, 0, 0);
}

// Stage R x 64-half tile (global row stride ldg halves) into LDS (row stride 64,
// XOR chunk swizzle: slot (row,c) holds global chunk c^(row&7)).
template <int R>
__device__ __forceinline__ void stage_tile(const _Float16* g, long ldg,
                                           _Float16* lds, int wave, int lane) {
    const int rl = lane >> 3;
    const int gc = (lane & 7) ^ rl;
#pragma unroll
    for (int i = 0; i < (R >> 5); ++i) {
        const int br = wave * (R >> 2) + i * 8;
        async_copy16(g + (long)(br + rl) * ldg + gc * 8, lds + br * 64);
    }
}

// ---------------- k_prep: all converts + transposes + bitmask pack ----------------
__device__ __forceinline__ void tr_tile(const float* __restrict__ in,
                                        _Float16* __restrict__ out, int R, int C,
                                        int br, int bc, int tid, float (*tile)[33]) {
    int tx = tid & 31, ty = tid >> 5;
#pragma unroll
    for (int i = 0; i < 32; i += 8)
        tile[ty + i][tx] = in[(size_t)(br + ty + i) * C + bc + tx];
    __syncthreads();
#pragma unroll
    for (int i = 0; i < 32; i += 8)
        out[(size_t)(bc + ty + i) * R + br + tx] = (_Float16)tile[tx][ty + i];
    __syncthreads();
}

__global__ __launch_bounds__(256) void k_prep(
    const float* __restrict__ search_x, const float* __restrict__ search_y,
    const float* __restrict__ query_x, const int* __restrict__ mask,
    const float* __restrict__ Wk, const float* __restrict__ Wq,
    _Float16* __restrict__ xh, _Float16* __restrict__ qh,
    _Float16* __restrict__ wkT, _Float16* __restrict__ wqT,
    _Float16* __restrict__ yT, unsigned int* __restrict__ bm) {
    __shared__ float tile[32][33];
    const int bx = blockIdx.x, tid = threadIdx.x;
    if (bx < 2048) {
        // pack mask 32M int32 -> 1M-word bitmask. Each thread builds 2 words
        // in-register from 8 independent int4 loads each (deep MLP, no ballot).
#pragma unroll
        for (int half = 0; half < 2; ++half) {
            const int w = bx * 512 + half * 256 + tid;
            const int4* mp = (const int4*)(mask + (size_t)w * 32);
            int4 m[8];
#pragma unroll
            for (int j = 0; j < 8; ++j) m[j] = mp[j];
            unsigned bits = 0;
#pragma unroll
            for (int j = 0; j < 8; ++j) {
                bits |= (m[j].x > 0 ? 1u : 0u) << (j * 4);
                bits |= (m[j].y > 0 ? 2u : 0u) << (j * 4);
                bits |= (m[j].z > 0 ? 4u : 0u) << (j * 4);
                bits |= (m[j].w > 0 ? 8u : 0u) << (j * 4);
            }
            bm[w] = bits;
        }
    } else if (bx < 2560) {
        const int base0 = (bx - 2048) * 256 + tid;
        for (int it = 0; it < 16; ++it) {
            const int i = (it * 512 * 256 + base0) * 4;
            float4 v = *(const float4*)(search_x + i);
            half4v h; h[0]=(_Float16)v.x; h[1]=(_Float16)v.y; h[2]=(_Float16)v.z; h[3]=(_Float16)v.w;
            *(half4v*)(xh + i) = h;
        }
    } else if (bx < 2816) {
        const int base0 = (bx - 2560) * 256 + tid;
        for (int it = 0; it < 16; ++it) {
            const int i = (it * 256 * 256 + base0) * 4;
            float4 v = *(const float4*)(query_x + i);
            half4v h; h[0]=(_Float16)v.x; h[1]=(_Float16)v.y; h[2]=(_Float16)v.z; h[3]=(_Float16)v.w;
            *(half4v*)(qh + i) = h;
        }
    } else if (bx < 2944) {
        for (int it = 0; it < 16; ++it) {
            const int t = (bx - 2816) * 16 + it;          // 2048 tiles
            tr_tile(search_y, yT, 8192, 256, (t >> 3) * 32, (t & 7) * 32, tid, tile);
        }
    } else if (bx < 2976) {
        for (int it = 0; it < 16; ++it) {
            const int t = (bx - 2944) * 16 + it;          // 512 tiles
            tr_tile(Wk, wkT, 1024, 512, (t >> 4) * 32, (t & 15) * 32, tid, tile);
        }
    } else {
        for (int it = 0; it < 16; ++it) {
            const int t = (bx - 2976) * 16 + it;
            tr_tile(Wq, wqT, 1024, 512, (t >> 4) * 32, (t & 15) * 32, tid, tile);
        }
    }
}

// ---------------- k_proj: keys = x@Wk and qk = q@Wq in one dispatch ----------------
// 128x128 tile, BK=64, ping-pong LDS (1 barrier/kt, staging overlaps MFMA).
__global__ __launch_bounds__(256, 2) void k_proj(const _Float16* __restrict__ xh,
                                                 const _Float16* __restrict__ qh,
                                                 const _Float16* __restrict__ wkT,
                                                 const _Float16* __restrict__ wqT,
                                                 _Float16* __restrict__ keys,
                                                 _Float16* __restrict__ qk) {
    __shared__ __align__(16) _Float16 As[2][128 * 64];
    __shared__ __align__(16) _Float16 Bs[2][128 * 64];
    const int tid = threadIdx.x, lane = tid & 63, wave = tid >> 6;
    const int wm = (wave >> 1) * 64, wn = (wave & 1) * 64;
    const int quad = lane >> 4, lr = lane & 15;
    const bool isK = blockIdx.y < 64;
    const _Float16* A = isK ? xh : qh;
    const _Float16* B = isK ? wkT : wqT;
    _Float16* C = isK ? keys : qk;
    const long m0 = (long)(isK ? blockIdx.y : blockIdx.y - 64) * 128;
    const long n0 = (long)blockIdx.x * 128;

    floatx4 acc[4][4] = {};
    stage_tile<128>(A + m0 * 1024, 1024, As[0], wave, lane);
    stage_tile<128>(B + n0 * 1024, 1024, Bs[0], wave, lane);
    for (int ktI = 0; ktI < 16; ++ktI) {
        __syncthreads();                      // drains stage of buf cb
        const int cb = ktI & 1;
        if (ktI < 15) {
            stage_tile<128>(A + m0 * 1024 + (ktI + 1) * 64, 1024, As[cb ^ 1], wave, lane);
            stage_tile<128>(B + n0 * 1024 + (ktI + 1) * 64, 1024, Bs[cb ^ 1], wave, lane);
        }
#pragma unroll
        for (int kk = 0; kk < 64; kk += 32) {
            const int sl = ((((kk >> 3) + quad) ^ (lr & 7)) * 8);
            half8v af[4], bf[4];
#pragma unroll
            for (int i = 0; i < 4; ++i) af[i] = *(const half8v*)&As[cb][(wm + i * 16 + lr) * 64 + sl];
#pragma unroll
            for (int j = 0; j < 4; ++j) bf[j] = *(const half8v*)&Bs[cb][(wn + j * 16 + lr) * 64 + sl];
#pragma unroll
            for (int i = 0; i < 4; ++i)
#pragma unroll
                for (int j = 0; j < 4; ++j)
                    acc[i][j] = __builtin_amdgcn_mfma_f32_16x16x32_f16(af[i], bf[j], acc[i][j], 0, 0, 0);
        }
    }
#pragma unroll
    for (int i = 0; i < 4; ++i) {
        long rbase = m0 + wm + i * 16 + quad * 4;
#pragma unroll
        for (int j = 0; j < 4; ++j) {
            long col = n0 + wn + j * 16 + lr;
#pragma unroll
            for (int r = 0; r < 4; ++r)
                C[(rbase + r) * 512 + col] = (_Float16)acc[i][j][r];
        }
    }
}

// ---------------- NT GEMM: C[M,N] = scale * A[M,K] @ B[N,K]^T ----------------
// R3-verified m97-style single-buffer structure; no min-waves bound (no spill).
// OUT_MODE 0: f16 store. OUT_MODE 1: fp32 partial store at C + blockIdx.z*M*N.
template <int OUT_MODE>
__global__ __launch_bounds__(256) void k_gemm_nt(const _Float16* __restrict__ A,
                                                 const _Float16* __restrict__ B,
                                                 void* __restrict__ C,
                                                 int M, int N, int K, int kChunk,
                                                 float scale) {
    __shared__ __align__(16) _Float16 As[128 * 64];
    __shared__ __align__(16) _Float16 Bs[128 * 64];
    const int tid = threadIdx.x, lane = tid & 63, wave = tid >> 6;
    const int wm = (wave >> 1) * 64, wn = (wave & 1) * 64;
    const int quad = lane >> 4, lr = lane & 15;
    const long m0 = (long)blockIdx.y * 128, n0 = (long)blockIdx.x * 128;
    const int kBegin = blockIdx.z * kChunk;
    const int kEnd   = kBegin + kChunk;

    floatx4 acc[4][4] = {};
    for (int kt = kBegin; kt < kEnd; kt += 64) {
        stage_tile<128>(A + m0 * K + kt, K, As, wave, lane);
        stage_tile<128>(B + n0 * K + kt, K, Bs, wave, lane);
        __syncthreads();
#pragma unroll
        for (int kk = 0; kk < 64; kk += 32) {
            const int sl = ((((kk >> 3) + quad) ^ (lr & 7)) * 8);
            half8v af[4], bf[4];
#pragma unroll
            for (int i = 0; i < 4; ++i) af[i] = *(const half8v*)&As[(wm + i * 16 + lr) * 64 + sl];
#pragma unroll
            for (int j = 0; j < 4; ++j) bf[j] = *(const half8v*)&Bs[(wn + j * 16 + lr) * 64 + sl];
#pragma unroll
            for (int i = 0; i < 4; ++i)
#pragma unroll
                for (int j = 0; j < 4; ++j)
                    acc[i][j] = __builtin_amdgcn_mfma_f32_16x16x32_f16(af[i], bf[j], acc[i][j], 0, 0, 0);
        }
        __syncthreads();
    }
#pragma unroll
    for (int i = 0; i < 4; ++i) {
        long rbase = m0 + wm + i * 16 + quad * 4;
#pragma unroll
        for (int j = 0; j < 4; ++j) {
            long col = n0 + wn + j * 16 + lr;
#pragma unroll
            for (int r = 0; r < 4; ++r) {
                float val = acc[i][j][r] * scale;
                if (OUT_MODE == 0)
                    ((_Float16*)C)[(rbase + r) * (long)N + col] = (_Float16)val;
                else
                    ((float*)C)[(size_t)blockIdx.z * M * N + (rbase + r) * (long)N + col] = val;
            }
        }
    }
}

// ------- masked softmax (bitmask), in-place on f16 logits [4096][8192] -------
__global__ __launch_bounds__(256) void k_softmax(_Float16* __restrict__ logits,
                                                 const unsigned int* __restrict__ bm) {
    const int q   = blockIdx.x;
    const int tid = threadIdx.x;
    _Float16* row = logits + (size_t)q * 8192;
    const unsigned int* bmr = bm + (size_t)q * 256;

    float v[32];
    unsigned mb = 0;
    float lmax = -3.0e38f;
#pragma unroll
    for (int i = 0; i < 8; ++i) {
        int base = i * 1024 + tid * 4;
        half4v h = *(const half4v*)(row + base);
        unsigned bits = (bmr[base >> 5] >> ((tid & 7) * 4)) & 0xFu;
#pragma unroll
        for (int j = 0; j < 4; ++j) {
            v[i * 4 + j] = (float)h[j];
            if ((bits >> j) & 1u) {
                mb |= 1u << (i * 4 + j);
                lmax = fmaxf(lmax, v[i * 4 + j]);
            }
        }
    }
#pragma unroll
    for (int off = 32; off > 0; off >>= 1) lmax = fmaxf(lmax, __shfl_xor(lmax, off, 64));
    __shared__ float redmax[4], redsum[4];
    if ((tid & 63) == 0) redmax[tid >> 6] = lmax;
    __syncthreads();
    lmax = fmaxf(fmaxf(redmax[0], redmax[1]), fmaxf(redmax[2], redmax[3]));

    float lsum = 0.f;
#pragma unroll
    for (int i = 0; i < 32; ++i) {
        float e = ((mb >> i) & 1u) ? __expf(v[i] - lmax) : 0.f;
        v[i] = e;
        lsum += e;
    }
#pragma unroll
    for (int off = 32; off > 0; off >>= 1) lsum += __shfl_xor(lsum, off, 64);
    if ((tid & 63) == 0) redsum[tid >> 6] = lsum;
    __syncthreads();
    lsum = redsum[0] + redsum[1] + redsum[2] + redsum[3];
    float inv = lsum > 0.f ? 1.f / lsum : 0.f;

#pragma unroll
    for (int i = 0; i < 8; ++i) {
        int base = i * 1024 + tid * 4;
        half4v h;
#pragma unroll
        for (int j = 0; j < 4; ++j) h[j] = (_Float16)(v[i * 4 + j] * inv);
        *(half4v*)(row + base) = h;
    }
}

// ---------------- sum 8 fp32 partials [8][n] -> out[n] ----------------
__global__ __launch_bounds__(256) void k_reduce8(const float* __restrict__ part,
                                                 float* __restrict__ out, int n) {
    int i = (blockIdx.x * 256 + threadIdx.x) * 4;
    if (i >= n) return;
    float4 s = *(const float4*)(part + i);
#pragma unroll
    for (int z = 1; z < 8; ++z) {
        float4 v = *(const float4*)(part + (size_t)z * n + i);
        s.x += v.x; s.y += v.y; s.z += v.z; s.w += v.w;
    }
    *(float4*)(out + i) = s;
}

extern "C" void kernel_launch(void* const* d_in, const int* in_sizes, int n_in,
                              void* d_out, int out_size, void* d_ws, size_t ws_size,
                              hipStream_t stream) {
    const float* search_x = (const float*)d_in[0];  // [8192,1024]
    const float* search_y = (const float*)d_in[1];  // [8192,256]
    const float* query_x  = (const float*)d_in[2];  // [4096,1024]
    const int*   mask     = (const int*)d_in[3];    // [4096,8192]
    const float* Wk       = (const float*)d_in[4];  // [1024,512]
    const float* Wq       = (const float*)d_in[5];  // [1024,512]
    (void)in_sizes; (void)n_in; (void)ws_size; (void)out_size;

    char* p = (char*)d_ws;
    _Float16* xh   = (_Float16*)p; p += (size_t)8192 * 1024 * 2;
    _Float16* qh   = (_Float16*)p; p += (size_t)4096 * 1024 * 2;
    _Float16* wkT  = (_Float16*)p; p += (size_t)512 * 1024 * 2;
    _Float16* wqT  = (_Float16*)p; p += (size_t)512 * 1024 * 2;
    _Float16* yT   = (_Float16*)p; p += (size_t)256 * 8192 * 2;
    _Float16* keys = (_Float16*)p; p += (size_t)8192 * 512 * 2;
    _Float16* qk   = (_Float16*)p; p += (size_t)4096 * 512 * 2;
    unsigned int* bmw = (unsigned int*)p; p += (size_t)4096 * 256 * 4;
    _Float16* lg   = (_Float16*)p; p += (size_t)4096 * 8192 * 2;
    float*    part = (float*)p;    p += (size_t)8 * 4096 * 256 * 4;

    // 1) converts + transposes + bitmask pack
    k_prep<<<3008, 256, 0, stream>>>(search_x, search_y, query_x, mask, Wk, Wq,
                                     xh, qh, wkT, wqT, yT, bmw);
    // 2) keys = x@Wk, qk = q@Wq (one dispatch)
    k_proj<<<dim3(4, 96), 256, 0, stream>>>(xh, qh, wkT, wqT, keys, qk);
    // 3) logits = (qk @ keys^T) / sqrt(512)
    k_gemm_nt<0><<<dim3(64, 32, 1), 256, 0, stream>>>(qk, keys, lg, 4096, 8192, 512, 512,
                                                      0.04419417382415922f);
    // 4) masked softmax in-place (bitmask)
    k_softmax<<<4096, 256, 0, stream>>>(lg, bmw);
    // 5) out = p @ y, split-K=8 -> fp32 partials, then reduce
    k_gemm_nt<1><<<dim3(2, 32, 8), 256, 0, stream>>>(lg, yT, part, 4096, 256, 8192, 1024, 1.0f);
    k_reduce8<<<1024, 256, 0, stream>>>(part, (float*)d_out, 4096 * 256);
}

// Round 8
// 370.346 us; speedup vs baseline: 1.5137x; 1.0210x over previous
//
#include <hip/hip_runtime.h>
#include <hip/hip_fp16.h>

typedef _Float16 half4v __attribute__((ext_vector_type(4)));
typedef _Float16 half8v __attribute__((ext_vector_type(8)));
typedef float floatx4 __attribute__((ext_vector_type(4)));

#define GLOBAL_AS __attribute__((address_space(1)))
#define LDS_AS __attribute__((address_space(3)))

__device__ __forceinline__ void async_copy16(const _Float16* g, _Float16* l) {
    __builtin_amdgcn_global_load_lds((const GLOBAL_AS unsigned int*)g,
                                     (LDS_AS unsigned int*)l, 16, 0, 0);
}

// Stage R x 64-half tile (global row stride ldg halves) into LDS (row stride 64,
// XOR chunk swizzle: slot (row,c) holds global chunk c^(row&7)).
template <int R>
__device__ __forceinline__ void stage_tile(const _Float16* g, long ldg,
                                           _Float16* lds, int wave, int lane) {
    const int rl = lane >> 3;
    const int gc = (lane & 7) ^ rl;
#pragma unroll
    for (int i = 0; i < (R >> 5); ++i) {
        const int br = wave * (R >> 2) + i * 8;
        async_copy16(g + (long)(br + rl) * ldg + gc * 8, lds + br * 64);
    }
}

// ---------------- k_prep: transposes (64x64/block, launched first) + converts ----------------
// One 64x64 f32->f16 transpose tile per block. LDS [64][64] unpadded: b128 writes
// 16B-aligned; read side t[r][c] has 16 distinct banks x 4-lane broadcast -> conflict-free.
__device__ __forceinline__ void tr64(const float* __restrict__ in,
                                     _Float16* __restrict__ out, int R, int C,
                                     int br, int bc, int tid, float (*t)[64]) {
    const int row = tid >> 4;            // 0..15
    const int col = (tid & 15) * 4;
#pragma unroll
    for (int rr = 0; rr < 64; rr += 16) {
        float4 v = *(const float4*)(in + (size_t)(br + row + rr) * C + bc + col);
        t[row + rr][col] = v.x; t[row + rr][col + 1] = v.y;
        t[row + rr][col + 2] = v.z; t[row + rr][col + 3] = v.w;
    }
    __syncthreads();
    const int c  = tid >> 2;             // out row 0..63
    const int q4 = (tid & 3) * 16;       // 16 halves per thread
    half8v h0, h1;
#pragma unroll
    for (int k = 0; k < 8; ++k) h0[k] = (_Float16)t[q4 + k][c];
#pragma unroll
    for (int k = 0; k < 8; ++k) h1[k] = (_Float16)t[q4 + 8 + k][c];
    *(half8v*)(out + (size_t)(bc + c) * R + br + q4) = h0;
    *(half8v*)(out + (size_t)(bc + c) * R + br + q4 + 8) = h1;
}

__global__ __launch_bounds__(256) void k_prep(
    const float* __restrict__ search_x, const float* __restrict__ search_y,
    const float* __restrict__ query_x,
    const float* __restrict__ Wk, const float* __restrict__ Wq,
    _Float16* __restrict__ xh, _Float16* __restrict__ qh,
    _Float16* __restrict__ wkT, _Float16* __restrict__ wqT,
    _Float16* __restrict__ yT) {
    __shared__ float tile[64][64];
    const int bx = blockIdx.x, tid = threadIdx.x;
    if (bx < 512) {                      // y: [8192,256] -> yT [256,8192]; 128x4 tiles
        const int t = bx;
        tr64(search_y, yT, 8192, 256, (t >> 2) * 64, (t & 3) * 64, tid, tile);
    } else if (bx < 640) {               // Wk: [1024,512] -> wkT [512,1024]; 16x8 tiles
        const int t = bx - 512;
        tr64(Wk, wkT, 1024, 512, (t >> 3) * 64, (t & 7) * 64, tid, tile);
    } else if (bx < 768) {               // Wq
        const int t = bx - 640;
        tr64(Wq, wqT, 1024, 512, (t >> 3) * 64, (t & 7) * 64, tid, tile);
    } else if (bx < 1280) {              // x convert
        const int base0 = (bx - 768) * 256 + tid;
        for (int it = 0; it < 16; ++it) {
            const int i = (it * 512 * 256 + base0) * 4;
            float4 v = *(const float4*)(search_x + i);
            half4v h; h[0]=(_Float16)v.x; h[1]=(_Float16)v.y; h[2]=(_Float16)v.z; h[3]=(_Float16)v.w;
            *(half4v*)(xh + i) = h;
        }
    } else {                             // q convert
        const int base0 = (bx - 1280) * 256 + tid;
        for (int it = 0; it < 16; ++it) {
            const int i = (it * 256 * 256 + base0) * 4;
            float4 v = *(const float4*)(query_x + i);
            half4v h; h[0]=(_Float16)v.x; h[1]=(_Float16)v.y; h[2]=(_Float16)v.z; h[3]=(_Float16)v.w;
            *(half4v*)(qh + i) = h;
        }
    }
}

// ---------------- k_proj: keys = x@Wk and qk = q@Wq in one dispatch ----------------
__global__ __launch_bounds__(256, 2) void k_proj(const _Float16* __restrict__ xh,
                                                 const _Float16* __restrict__ qh,
                                                 const _Float16* __restrict__ wkT,
                                                 const _Float16* __restrict__ wqT,
                                                 _Float16* __restrict__ keys,
                                                 _Float16* __restrict__ qk) {
    __shared__ __align__(16) _Float16 As[2][128 * 64];
    __shared__ __align__(16) _Float16 Bs[2][128 * 64];
    const int tid = threadIdx.x, lane = tid & 63, wave = tid >> 6;
    const int wm = (wave >> 1) * 64, wn = (wave & 1) * 64;
    const int quad = lane >> 4, lr = lane & 15;
    const bool isK = blockIdx.y < 64;
    const _Float16* A = isK ? xh : qh;
    const _Float16* B = isK ? wkT : wqT;
    _Float16* C = isK ? keys : qk;
    const long m0 = (long)(isK ? blockIdx.y : blockIdx.y - 64) * 128;
    const long n0 = (long)blockIdx.x * 128;

    floatx4 acc[4][4] = {};
    stage_tile<128>(A + m0 * 1024, 1024, As[0], wave, lane);
    stage_tile<128>(B + n0 * 1024, 1024, Bs[0], wave, lane);
    for (int ktI = 0; ktI < 16; ++ktI) {
        __syncthreads();
        const int cb = ktI & 1;
        if (ktI < 15) {
            stage_tile<128>(A + m0 * 1024 + (ktI + 1) * 64, 1024, As[cb ^ 1], wave, lane);
            stage_tile<128>(B + n0 * 1024 + (ktI + 1) * 64, 1024, Bs[cb ^ 1], wave, lane);
        }
#pragma unroll
        for (int kk = 0; kk < 64; kk += 32) {
            const int sl = ((((kk >> 3) + quad) ^ (lr & 7)) * 8);
            half8v af[4], bf[4];
#pragma unroll
            for (int i = 0; i < 4; ++i) af[i] = *(const half8v*)&As[cb][(wm + i * 16 + lr) * 64 + sl];
#pragma unroll
            for (int j = 0; j < 4; ++j) bf[j] = *(const half8v*)&Bs[cb][(wn + j * 16 + lr) * 64 + sl];
#pragma unroll
            for (int i = 0; i < 4; ++i)
#pragma unroll
                for (int j = 0; j < 4; ++j)
                    acc[i][j] = __builtin_amdgcn_mfma_f32_16x16x32_f16(af[i], bf[j], acc[i][j], 0, 0, 0);
        }
    }
#pragma unroll
    for (int i = 0; i < 4; ++i) {
        long rbase = m0 + wm + i * 16 + quad * 4;
#pragma unroll
        for (int j = 0; j < 4; ++j) {
            long col = n0 + wn + j * 16 + lr;
#pragma unroll
            for (int r = 0; r < 4; ++r)
                C[(rbase + r) * 512 + col] = (_Float16)acc[i][j][r];
        }
    }
}

// ---------------- NT GEMM: C[M,N] = scale * A[M,K] @ B[N,K]^T ----------------
// OUT_MODE 1: fp32 partial store at C + blockIdx.z*M*N (split-K).
// OUT_MODE 2: masked f16 store (logits): masked entries get sentinel -65504,
// which underflows to p=0 exactly in softmax -> matches where(m,p,0).
template <int OUT_MODE>
__global__ __launch_bounds__(256) void k_gemm_nt(const _Float16* __restrict__ A,
                                                 const _Float16* __restrict__ B,
                                                 void* __restrict__ C,
                                                 const int* __restrict__ mask,
                                                 int M, int N, int K, int kChunk,
                                                 float scale) {
    __shared__ __align__(16) _Float16 As[128 * 64];
    __shared__ __align__(16) _Float16 Bs[128 * 64];
    const int tid = threadIdx.x, lane = tid & 63, wave = tid >> 6;
    const int wm = (wave >> 1) * 64, wn = (wave & 1) * 64;
    const int quad = lane >> 4, lr = lane & 15;
    const long m0 = (long)blockIdx.y * 128, n0 = (long)blockIdx.x * 128;
    const int kBegin = blockIdx.z * kChunk;
    const int kEnd   = kBegin + kChunk;

    floatx4 acc[4][4] = {};
    for (int kt = kBegin; kt < kEnd; kt += 64) {
        stage_tile<128>(A + m0 * K + kt, K, As, wave, lane);
        stage_tile<128>(B + n0 * K + kt, K, Bs, wave, lane);
        __syncthreads();
#pragma unroll
        for (int kk = 0; kk < 64; kk += 32) {
            const int sl = ((((kk >> 3) + quad) ^ (lr & 7)) * 8);
            half8v af[4], bf[4];
#pragma unroll
            for (int i = 0; i < 4; ++i) af[i] = *(const half8v*)&As[(wm + i * 16 + lr) * 64 + sl];
#pragma unroll
            for (int j = 0; j < 4; ++j) bf[j] = *(const half8v*)&Bs[(wn + j * 16 + lr) * 64 + sl];
#pragma unroll
            for (int i = 0; i < 4; ++i)
#pragma unroll
                for (int j = 0; j < 4; ++j)
                    acc[i][j] = __builtin_amdgcn_mfma_f32_16x16x32_f16(af[i], bf[j], acc[i][j], 0, 0, 0);
        }
        __syncthreads();
    }
#pragma unroll
    for (int i = 0; i < 4; ++i) {
        long rbase = m0 + wm + i * 16 + quad * 4;
#pragma unroll
        for (int j = 0; j < 4; ++j) {
            long col = n0 + wn + j * 16 + lr;
#pragma unroll
            for (int r = 0; r < 4; ++r) {
                float val = acc[i][j][r] * scale;
                if (OUT_MODE == 2) {
                    const int mk = mask[(rbase + r) * 8192L + col];
                    ((_Float16*)C)[(rbase + r) * (long)N + col] =
                        (mk > 0) ? (_Float16)val : (_Float16)(-65504.f);
                } else {
                    ((float*)C)[(size_t)blockIdx.z * M * N + (rbase + r) * (long)N + col] = val;
                }
            }
        }
    }
}

// ------- softmax, in-place on f16 logits [4096][8192]; mask pre-applied as -65504 -------
__global__ __launch_bounds__(256) void k_softmax(_Float16* __restrict__ logits) {
    const int q   = blockIdx.x;
    const int tid = threadIdx.x;
    _Float16* row = logits + (size_t)q * 8192;

    float v[32];
    float lmax = -3.0e38f;
#pragma unroll
    for (int i = 0; i < 8; ++i) {
        int base = i * 1024 + tid * 4;
        half4v h = *(const half4v*)(row + base);
#pragma unroll
        for (int j = 0; j < 4; ++j) {
            v[i * 4 + j] = (float)h[j];
            lmax = fmaxf(lmax, v[i * 4 + j]);
        }
    }
#pragma unroll
    for (int off = 32; off > 0; off >>= 1) lmax = fmaxf(lmax, __shfl_xor(lmax, off, 64));
    __shared__ float redmax[4], redsum[4];
    if ((tid & 63) == 0) redmax[tid >> 6] = lmax;
    __syncthreads();
    lmax = fmaxf(fmaxf(redmax[0], redmax[1]), fmaxf(redmax[2], redmax[3]));

    float lsum = 0.f;
#pragma unroll
    for (int i = 0; i < 32; ++i) {
        float e = __expf(v[i] - lmax);   // masked: exp(-65504 - m) == 0.0f exactly
        v[i] = e;
        lsum += e;
    }
#pragma unroll
    for (int off = 32; off > 0; off >>= 1) lsum += __shfl_xor(lsum, off, 64);
    if ((tid & 63) == 0) redsum[tid >> 6] = lsum;
    __syncthreads();
    lsum = redsum[0] + redsum[1] + redsum[2] + redsum[3];
    float inv = lsum > 0.f ? 1.f / lsum : 0.f;

#pragma unroll
    for (int i = 0; i < 8; ++i) {
        int base = i * 1024 + tid * 4;
        half4v h;
#pragma unroll
        for (int j = 0; j < 4; ++j) h[j] = (_Float16)(v[i * 4 + j] * inv);
        *(half4v*)(row + base) = h;
    }
}

// ---------------- sum 8 fp32 partials [8][n] -> out[n] ----------------
__global__ __launch_bounds__(256) void k_reduce8(const float* __restrict__ part,
                                                 float* __restrict__ out, int n) {
    int i = (blockIdx.x * 256 + threadIdx.x) * 4;
    if (i >= n) return;
    float4 s = *(const float4*)(part + i);
#pragma unroll
    for (int z = 1; z < 8; ++z) {
        float4 v = *(const float4*)(part + (size_t)z * n + i);
        s.x += v.x; s.y += v.y; s.z += v.z; s.w += v.w;
    }
    *(float4*)(out + i) = s;
}

extern "C" void kernel_launch(void* const* d_in, const int* in_sizes, int n_in,
                              void* d_out, int out_size, void* d_ws, size_t ws_size,
                              hipStream_t stream) {
    const float* search_x = (const float*)d_in[0];  // [8192,1024]
    const float* search_y = (const float*)d_in[1];  // [8192,256]
    const float* query_x  = (const float*)d_in[2];  // [4096,1024]
    const int*   mask     = (const int*)d_in[3];    // [4096,8192]
    const float* Wk       = (const float*)d_in[4];  // [1024,512]
    const float* Wq       = (const float*)d_in[5];  // [1024,512]
    (void)in_sizes; (void)n_in; (void)ws_size; (void)out_size;

    char* p = (char*)d_ws;
    _Float16* xh   = (_Float16*)p; p += (size_t)8192 * 1024 * 2;
    _Float16* qh   = (_Float16*)p; p += (size_t)4096 * 1024 * 2;
    _Float16* wkT  = (_Float16*)p; p += (size_t)512 * 1024 * 2;
    _Float16* wqT  = (_Float16*)p; p += (size_t)512 * 1024 * 2;
    _Float16* yT   = (_Float16*)p; p += (size_t)256 * 8192 * 2;
    _Float16* keys = (_Float16*)p; p += (size_t)8192 * 512 * 2;
    _Float16* qk   = (_Float16*)p; p += (size_t)4096 * 512 * 2;
    _Float16* lg   = (_Float16*)p; p += (size_t)4096 * 8192 * 2;
    float*    part = (float*)p;    p += (size_t)8 * 4096 * 256 * 4;

    // 1) transposes (first: longest-latency blocks) + converts
    k_prep<<<1536, 256, 0, stream>>>(search_x, search_y, query_x, Wk, Wq,
                                     xh, qh, wkT, wqT, yT);
    // 2) keys = x@Wk, qk = q@Wq (one dispatch)
    k_proj<<<dim3(4, 96), 256, 0, stream>>>(xh, qh, wkT, wqT, keys, qk);
    // 3) logits = (qk @ keys^T)/sqrt(512), mask applied in epilogue (sentinel -65504)
    k_gemm_nt<2><<<dim3(64, 32, 1), 256, 0, stream>>>(qk, keys, lg, mask, 4096, 8192, 512, 512,
                                                      0.04419417382415922f);
    // 4) softmax in-place (no mask needed; masked entries underflow to 0)
    k_softmax<<<4096, 256, 0, stream>>>(lg);
    // 5) out = p @ y, split-K=8 -> fp32 partials, then reduce
    k_gemm_nt<1><<<dim3(2, 32, 8), 256, 0, stream>>>(lg, yT, part, nullptr, 4096, 256, 8192, 1024, 1.0f);
    k_reduce8<<<1024, 256, 0, stream>>>(part, (float*)d_out, 4096 * 256);
}